// Round 2
// baseline (387.207 us; speedup 1.0000x reference)
//
#include <hip/hip_runtime.h>
#include <hip/hip_bf16.h>
#include <stdint.h>

// B=8, C=256, HW=16384, HEADS=4, HEAD_DIM=64, SCALE=1/8.
// Restructure: G[b]=x x^T (split-bf16 MFMA, fp32-accurate);
// logits = Wq G Wk^T (+bias terms via rowsum s); attn = softmax;
// M = Wproj blockdiag(attn); P = M Wv; out = P x + (M bv + bproj).

#define HW 16384
#define SCALE_F 0.125f
#define NF 16384.0f

typedef __attribute__((ext_vector_type(8))) short bf16x8;
typedef __attribute__((ext_vector_type(4))) float f32x4;

__device__ __forceinline__ unsigned short f2bf(float f) {
    union { float f; uint32_t u; } v; v.f = f;
    uint32_t u = v.u;
    return (unsigned short)((u + 0x7fffu + ((u >> 16) & 1u)) >> 16);  // RNE
}
__device__ __forceinline__ float bf2f(unsigned short s) {
    union { uint32_t u; float f; } v; v.u = ((uint32_t)s) << 16;
    return v.f;
}

// ---------------- K1: cast x -> x_hi, x_lo (bf16) + row sums s[b*256+c]
__global__ __launch_bounds__(256) void cast_x(
        const float* __restrict__ x, unsigned short* __restrict__ xh,
        unsigned short* __restrict__ xl, float* __restrict__ s) {
    const int row = blockIdx.x;          // b*256+c, 2048 rows
    const int tid = threadIdx.x;
    const float* xr = x + (size_t)row * HW;
    unsigned short* xhr = xh + (size_t)row * HW;
    unsigned short* xlr = xl + (size_t)row * HW;
    float loc = 0.f;
    #pragma unroll
    for (int p = 0; p < 16; ++p) {
        const int i4 = (p * 256 + tid) * 4;
        const float4 v = *reinterpret_cast<const float4*>(xr + i4);
        ushort4 hpk, lpk;
        hpk.x = f2bf(v.x); lpk.x = f2bf(v.x - bf2f(hpk.x));
        hpk.y = f2bf(v.y); lpk.y = f2bf(v.y - bf2f(hpk.y));
        hpk.z = f2bf(v.z); lpk.z = f2bf(v.z - bf2f(hpk.z));
        hpk.w = f2bf(v.w); lpk.w = f2bf(v.w - bf2f(hpk.w));
        *reinterpret_cast<ushort4*>(xhr + i4) = hpk;
        *reinterpret_cast<ushort4*>(xlr + i4) = lpk;
        loc += (v.x + v.y) + (v.z + v.w);
    }
    __shared__ float red[256];
    red[tid] = loc;
    __syncthreads();
    for (int st = 128; st > 0; st >>= 1) {
        if (tid < st) red[tid] += red[tid + st];
        __syncthreads();
    }
    if (tid == 0) s[row] = red[0];
}

// ---------------- K2: partG[b][kc] += X_tile X_tile^T over K-chunk (split-bf16, 3 passes)
__global__ __launch_bounds__(256) void gram(
        const unsigned short* __restrict__ xh, const unsigned short* __restrict__ xl,
        float* __restrict__ partG) {
    const int tile = blockIdx.x;   // 0..3 -> (mt,nt)
    const int kc   = blockIdx.y;   // 0..15 (K-chunk of 1024)
    const int b    = blockIdx.z;
    const int m0 = (tile >> 1) * 128, n0 = (tile & 1) * 128;
    __shared__ __align__(16) unsigned short Ah[128 * 40];
    __shared__ __align__(16) unsigned short Al[128 * 40];
    __shared__ __align__(16) unsigned short Bh[128 * 40];
    __shared__ __align__(16) unsigned short Bl[128 * 40];
    const int tid = threadIdx.x, lane = tid & 63, wid = tid >> 6;
    const int wm = (wid >> 1) * 64, wn = (wid & 1) * 64;
    const int l15 = lane & 15, lg = lane >> 4;
    const size_t xbase = (size_t)b * 256 * HW;
    const int r = tid >> 3, c4 = (tid & 7) * 4;
    f32x4 acc[4][4] = {};

    for (int ks = 0; ks < 32; ++ks) {
        const int k0 = kc * 1024 + ks * 32;
        #pragma unroll
        for (int p = 0; p < 4; ++p) {
            const int row = r + p * 32;
            const size_t offA = xbase + (size_t)(m0 + row) * HW + k0 + c4;
            const size_t offB = xbase + (size_t)(n0 + row) * HW + k0 + c4;
            *reinterpret_cast<ushort4*>(&Ah[row * 40 + c4]) = *reinterpret_cast<const ushort4*>(xh + offA);
            *reinterpret_cast<ushort4*>(&Al[row * 40 + c4]) = *reinterpret_cast<const ushort4*>(xl + offA);
            *reinterpret_cast<ushort4*>(&Bh[row * 40 + c4]) = *reinterpret_cast<const ushort4*>(xh + offB);
            *reinterpret_cast<ushort4*>(&Bl[row * 40 + c4]) = *reinterpret_cast<const ushort4*>(xl + offB);
        }
        __syncthreads();
        bf16x8 fah[4], fal[4], fbh[4], fbl[4];
        #pragma unroll
        for (int i = 0; i < 4; ++i) {
            const int rowA = (wm + i * 16 + l15) * 40 + lg * 8;
            fah[i] = *reinterpret_cast<const bf16x8*>(&Ah[rowA]);
            fal[i] = *reinterpret_cast<const bf16x8*>(&Al[rowA]);
        }
        #pragma unroll
        for (int j = 0; j < 4; ++j) {
            const int rowB = (wn + j * 16 + l15) * 40 + lg * 8;
            fbh[j] = *reinterpret_cast<const bf16x8*>(&Bh[rowB]);
            fbl[j] = *reinterpret_cast<const bf16x8*>(&Bl[rowB]);
        }
        #pragma unroll
        for (int i = 0; i < 4; ++i)
            #pragma unroll
            for (int j = 0; j < 4; ++j) {
                acc[i][j] = __builtin_amdgcn_mfma_f32_16x16x32_bf16(fah[i], fbh[j], acc[i][j], 0, 0, 0);
                acc[i][j] = __builtin_amdgcn_mfma_f32_16x16x32_bf16(fah[i], fbl[j], acc[i][j], 0, 0, 0);
                acc[i][j] = __builtin_amdgcn_mfma_f32_16x16x32_bf16(fal[i], fbh[j], acc[i][j], 0, 0, 0);
            }
        __syncthreads();
    }
    float* pw = partG + (size_t)(b * 16 + kc) * 65536;
    #pragma unroll
    for (int i = 0; i < 4; ++i)
        #pragma unroll
        for (int rr = 0; rr < 4; ++rr) {
            const int m = m0 + wm + i * 16 + lg * 4 + rr;
            #pragma unroll
            for (int j = 0; j < 4; ++j)
                pw[m * 256 + n0 + wn + j * 16 + l15] = acc[i][j][rr];
        }
}

// ---------------- K3: G = sum over 16 chunks of partG
__global__ __launch_bounds__(256) void greduce(
        const float* __restrict__ partG, float* __restrict__ G) {
    const size_t idx = (size_t)blockIdx.x * 256 + threadIdx.x;  // 524288
    const int b = (int)(idx >> 16);
    const int i = (int)(idx & 65535);
    float sacc = 0.f;
    #pragma unroll
    for (int kc = 0; kc < 16; ++kc)
        sacc += partG[(size_t)(b * 16 + kc) * 65536 + i];
    G[idx] = sacc;
}

// ---------------- K4: logits = SCALE*(Wq G Wk^T + bias terms); softmax -> attn (fp32)
__global__ __launch_bounds__(256) void attn_fold(
        const float* __restrict__ G, const float* __restrict__ s,
        const float* __restrict__ Wqkv, const float* __restrict__ bqkv,
        float* __restrict__ attn) {
    const int bh = blockIdx.x, b = bh >> 2, h = bh & 3;
    const int tid = threadIdx.x;
    __shared__ float smem[24704];            // 98.8 KB
    float* Wqt = smem;                       // phase1: [256][64]
    float* Gs  = smem + 16384;               // phase1: [32][256]
    float* t1  = smem;                       // phase2: [64][257] (overlaps Wqt)
    float* lg  = smem + 16448;               // [64][65]
    float* qs  = smem + 24576;               // 64
    float* ks  = smem + 24640;               // 64
    const float* Gb = G + (size_t)b * 65536;
    const float* Wq = Wqkv + (size_t)(h * 64) * 256;
    const float* Wk = Wqkv + (size_t)(256 + h * 64) * 256;

    // stage Wq transposed: Wqt[c][d] = Wq[d][c]
    {
        const int d = tid & 63, cb = tid >> 6;
        for (int j = 0; j < 64; ++j)
            Wqt[(cb * 64 + j) * 64 + d] = Wq[(size_t)d * 256 + cb * 64 + j];
    }

    // phase1: t1[d][cp] = sum_c Wq[d][c] G[c][cp]; thread owns column cp
    float acc[64];
    #pragma unroll
    for (int d = 0; d < 64; ++d) acc[d] = 0.f;
    const int cp = tid;
    for (int cb = 0; cb < 8; ++cb) {
        __syncthreads();   // Wqt visible (1st iter) / prev Gs readers done
        {
            const int rr = tid >> 3, cc = (tid & 7) * 32;
            #pragma unroll
            for (int j = 0; j < 8; ++j)
                *reinterpret_cast<float4*>(&Gs[rr * 256 + cc + j * 4]) =
                    *reinterpret_cast<const float4*>(Gb + (size_t)(cb * 32 + rr) * 256 + cc + j * 4);
        }
        __syncthreads();
        for (int c = 0; c < 32; ++c) {
            const float gv = Gs[c * 256 + cp];
            const float4* wr = reinterpret_cast<const float4*>(&Wqt[(cb * 32 + c) * 64]);
            #pragma unroll
            for (int d4 = 0; d4 < 16; ++d4) {
                const float4 w = wr[d4];
                acc[d4 * 4 + 0] += w.x * gv;
                acc[d4 * 4 + 1] += w.y * gv;
                acc[d4 * 4 + 2] += w.z * gv;
                acc[d4 * 4 + 3] += w.w * gv;
            }
        }
    }
    __syncthreads();       // phase1 reads complete before t1 overwrites Wqt
    #pragma unroll
    for (int d = 0; d < 64; ++d) t1[d * 257 + cp] = acc[d];
    // qs = Wq s, ks = Wk s (bias path; zero when bqkv==0 but computed for generality)
    if (tid < 128) {
        const int d = tid & 63;
        const float* wr = (tid < 64) ? (Wq + (size_t)d * 256) : (Wk + (size_t)d * 256);
        const float* sb = s + b * 256;
        float a = 0.f;
        for (int c = 0; c < 256; ++c) a += wr[c] * sb[c];
        if (tid < 64) qs[d] = a; else ks[d] = a;
    }
    __syncthreads();

    // phase2: logits[d][e] = sum_cp t1[d][cp] Wk[e][cp]; thread = (e16=tid>>6, d=tid&63)
    const int d = tid & 63, e16 = tid >> 6;
    float acc2[16];
    #pragma unroll
    for (int i = 0; i < 16; ++i) acc2[i] = 0.f;
    const float* wkbase = Wk + (size_t)(e16 * 16) * 256;
    for (int c2 = 0; c2 < 256; ++c2) {
        const float tv = t1[d * 257 + c2];
        #pragma unroll
        for (int i = 0; i < 16; ++i)
            acc2[i] += tv * wkbase[(size_t)i * 256 + c2];
    }
    const float* bq = bqkv + h * 64;
    const float* bk = bqkv + 256 + h * 64;
    #pragma unroll
    for (int i = 0; i < 16; ++i) {
        const int e = e16 * 16 + i;
        lg[d * 65 + e] = SCALE_F * (acc2[i] + bq[d] * ks[e] + bk[e] * qs[d] + NF * bq[d] * bk[e]);
    }
    __syncthreads();
    if (tid < 64) {
        float m = -1e30f;
        for (int e = 0; e < 64; ++e) m = fmaxf(m, lg[tid * 65 + e]);
        float sum = 0.f;
        for (int e = 0; e < 64; ++e) {
            const float ex = __expf(lg[tid * 65 + e] - m);
            sum += ex;
            lg[tid * 65 + e] = ex;
        }
        const float inv = 1.f / sum;
        float* ar = attn + ((size_t)bh * 64 + tid) * 64;
        for (int e = 0; e < 64; ++e) ar[e] = lg[tid * 65 + e] * inv;
    }
}

// ---------------- K5: M[b][o][h*64+e] = sum_d Wproj[o][h*64+d] attn[b,h,d,e] (fp32)
__global__ __launch_bounds__(256) void build_M(
        const float* __restrict__ attn, const float* __restrict__ Wproj,
        float* __restrict__ M) {
    const int g = blockIdx.x * 256 + threadIdx.x;
    const int b = g >> 16, o = (g >> 8) & 255, cpx = g & 255;
    const int h = cpx >> 6, e = cpx & 63;
    const float* wrow = Wproj + (size_t)o * 256 + h * 64;
    const float* acol = attn + ((size_t)(b * 4 + h) * 64) * 64 + e;
    float sacc = 0.f;
    #pragma unroll
    for (int d = 0; d < 64; ++d) sacc += wrow[d] * acol[d * 64];
    M[g] = sacc;
}

// ---------------- K6: P[b] = M[b] Wv (bf16); cvec[b] = M[b] bv + bproj
__global__ __launch_bounds__(256) void build_P(
        const float* __restrict__ M, const float* __restrict__ Wqkv,
        const float* __restrict__ bqkv, const float* __restrict__ bproj,
        unsigned short* __restrict__ P, float* __restrict__ cvec) {
    const int b = blockIdx.x >> 4, oc = blockIdx.x & 15;   // 16 o-rows per block
    const int tid = threadIdx.x, c = tid;
    __shared__ float Wvs[32 * 256];
    __shared__ float Ms[16 * 256];
    for (int j = tid; j < 16 * 256; j += 256)
        Ms[j] = M[(size_t)b * 65536 + oc * 16 * 256 + j];
    float acc[16];
    #pragma unroll
    for (int o = 0; o < 16; ++o) acc[o] = 0.f;
    for (int cb2 = 0; cb2 < 8; ++cb2) {
        __syncthreads();
        for (int j = tid; j < 32 * 256; j += 256)
            Wvs[j] = Wqkv[(size_t)(512 + cb2 * 32) * 256 + j];
        __syncthreads();
        for (int c2 = 0; c2 < 32; ++c2) {
            const float wv = Wvs[c2 * 256 + c];
            #pragma unroll
            for (int o = 0; o < 16; ++o)
                acc[o] += Ms[o * 256 + cb2 * 32 + c2] * wv;
        }
    }
    #pragma unroll
    for (int o = 0; o < 16; ++o)
        P[(size_t)b * 65536 + (size_t)(oc * 16 + o) * 256 + c] = f2bf(acc[o]);
    if (tid < 16) {
        const int o = oc * 16 + tid;
        float a = bproj[o];
        for (int c2 = 0; c2 < 256; ++c2)
            a += M[(size_t)b * 65536 + (size_t)o * 256 + c2] * bqkv[512 + c2];
        cvec[b * 256 + o] = a;
    }
}

// ---------------- K7: out[b][o][n] = sum_c P[b][o][c] x_hi[b][c][n] + cvec[b][o]
__global__ __launch_bounds__(256) void out_gemm(
        const unsigned short* __restrict__ P, const unsigned short* __restrict__ xh,
        const float* __restrict__ cvec, float* __restrict__ out) {
    const int n0 = blockIdx.x * 128;
    const int m0 = blockIdx.y * 128;
    const int b  = blockIdx.z;
    __shared__ __align__(16) unsigned short As[128 * 40];
    __shared__ __align__(16) unsigned short Bs[128 * 40];
    const int tid = threadIdx.x, lane = tid & 63, wid = tid >> 6;
    const int wm = (wid >> 1) * 64, wn = (wid & 1) * 64;
    const int l15 = lane & 15, lg = lane >> 4;
    const unsigned short* Pb = P + (size_t)b * 65536;
    const unsigned short* xb = xh + (size_t)b * 256 * HW;
    f32x4 acc[4][4] = {};

    for (int k0 = 0; k0 < 256; k0 += 32) {
        {
            const int r = tid >> 3, c4 = (tid & 7) * 4;
            #pragma unroll
            for (int p = 0; p < 4; ++p) {
                const int row = r + p * 32;
                *reinterpret_cast<ushort4*>(&As[row * 40 + c4]) =
                    *reinterpret_cast<const ushort4*>(Pb + (size_t)(m0 + row) * 256 + k0 + c4);
            }
        }
        {
            const int n = tid & 127, kq = (tid >> 7) * 4;
            #pragma unroll
            for (int p = 0; p < 4; ++p) {
                const int kk = p * 8 + kq;
                ushort4 pk;
                pk.x = xb[(size_t)(k0 + kk + 0) * HW + n0 + n];
                pk.y = xb[(size_t)(k0 + kk + 1) * HW + n0 + n];
                pk.z = xb[(size_t)(k0 + kk + 2) * HW + n0 + n];
                pk.w = xb[(size_t)(k0 + kk + 3) * HW + n0 + n];
                *reinterpret_cast<ushort4*>(&Bs[n * 40 + kk]) = pk;
            }
        }
        __syncthreads();
        bf16x8 fa[4], fb[4];
        #pragma unroll
        for (int i = 0; i < 4; ++i)
            fa[i] = *reinterpret_cast<const bf16x8*>(&As[(wm + i * 16 + l15) * 40 + lg * 8]);
        #pragma unroll
        for (int j = 0; j < 4; ++j)
            fb[j] = *reinterpret_cast<const bf16x8*>(&Bs[(wn + j * 16 + l15) * 40 + lg * 8]);
        #pragma unroll
        for (int i = 0; i < 4; ++i)
            #pragma unroll
            for (int j = 0; j < 4; ++j)
                acc[i][j] = __builtin_amdgcn_mfma_f32_16x16x32_bf16(fa[i], fb[j], acc[i][j], 0, 0, 0);
        __syncthreads();
    }
    float* ob = out + (size_t)b * 256 * HW;
    #pragma unroll
    for (int i = 0; i < 4; ++i)
        #pragma unroll
        for (int rr = 0; rr < 4; ++rr) {
            const int m = m0 + wm + i * 16 + lg * 4 + rr;
            const float bp = cvec[b * 256 + m];
            #pragma unroll
            for (int j = 0; j < 4; ++j) {
                const int n = n0 + wn + j * 16 + l15;
                ob[(size_t)m * HW + n] = acc[i][j][rr] + bp;
            }
        }
}

extern "C" void kernel_launch(void* const* d_in, const int* in_sizes, int n_in,
                              void* d_out, int out_size, void* d_ws, size_t ws_size,
                              hipStream_t stream) {
    const float* x     = (const float*)d_in[0];
    const float* Wqkv  = (const float*)d_in[1];
    const float* bqkv  = (const float*)d_in[2];
    const float* Wproj = (const float*)d_in[3];
    const float* bproj = (const float*)d_in[4];
    float* out = (float*)d_out;

    // ws layout (bytes):
    //   x_hi  :         0  67108864
    //   x_lo  :  67108864  67108864
    //   partG : 134217728  33554432   (8*16*256*256 f32)
    //   G     : 167772160   2097152
    //   attn  : 169869312    524288
    //   M     : 170393600   2097152
    //   P     : 172490752   1048576
    //   cvec  : 173539328      8192
    //   s     : 173547520      8192   -> total ~165.6 MiB
    char* ws = (char*)d_ws;
    unsigned short* xh = (unsigned short*)(ws);
    unsigned short* xl = (unsigned short*)(ws + 67108864);
    float* partG = (float*)(ws + 134217728);
    float* G     = (float*)(ws + 167772160);
    float* attn  = (float*)(ws + 169869312);
    float* M     = (float*)(ws + 170393600);
    unsigned short* P = (unsigned short*)(ws + 172490752);
    float* cvec  = (float*)(ws + 173539328);
    float* s     = (float*)(ws + 173547520);

    cast_x   <<<2048,            256, 0, stream>>>(x, xh, xl, s);
    gram     <<<dim3(4, 16, 8),  256, 0, stream>>>(xh, xl, partG);
    greduce  <<<2048,            256, 0, stream>>>(partG, G);
    attn_fold<<<32,              256, 0, stream>>>(G, s, Wqkv, bqkv, attn);
    build_M  <<<2048,            256, 0, stream>>>(attn, Wproj, M);
    build_P  <<<128,             256, 0, stream>>>(M, Wqkv, bqkv, bproj, P, cvec);
    out_gemm <<<dim3(128, 2, 8), 256, 0, stream>>>(P, xh, cvec, out);
}

// Round 3
// 292.523 us; speedup vs baseline: 1.3237x; 1.3237x over previous
//
#include <hip/hip_runtime.h>
#include <hip/hip_bf16.h>
#include <stdint.h>

// B=8, C=256, HW=16384, HEADS=4, HEAD_DIM=64, SCALE=1/8.
// Restructure: G[b]=x x^T (split-bf16 MFMA, fp32-accurate);
// T[b] = Wq_all G[b]; logits = T_h Wk_h^T (+bias terms); attn = softmax;
// M = Wproj blockdiag(attn); P = M Wv; out = P x + (M bv + bproj).

#define HW 16384
#define SCALE_F 0.125f
#define NF 16384.0f

typedef __attribute__((ext_vector_type(8))) short bf16x8;
typedef __attribute__((ext_vector_type(4))) float f32x4;

__device__ __forceinline__ unsigned short f2bf(float f) {
    union { float f; uint32_t u; } v; v.f = f;
    uint32_t u = v.u;
    return (unsigned short)((u + 0x7fffu + ((u >> 16) & 1u)) >> 16);  // RNE
}
__device__ __forceinline__ float bf2f(unsigned short s) {
    union { uint32_t u; float f; } v; v.u = ((uint32_t)s) << 16;
    return v.f;
}

// ---------------- K1: cast x -> x_hi, x_lo (bf16) + row sums s[b*256+c]
__global__ __launch_bounds__(256) void cast_x(
        const float* __restrict__ x, unsigned short* __restrict__ xh,
        unsigned short* __restrict__ xl, float* __restrict__ s) {
    const int row = blockIdx.x;          // b*256+c, 2048 rows
    const int tid = threadIdx.x;
    const float* xr = x + (size_t)row * HW;
    unsigned short* xhr = xh + (size_t)row * HW;
    unsigned short* xlr = xl + (size_t)row * HW;
    float loc = 0.f;
    #pragma unroll
    for (int p = 0; p < 16; ++p) {
        const int i4 = (p * 256 + tid) * 4;
        const float4 v = *reinterpret_cast<const float4*>(xr + i4);
        ushort4 hpk, lpk;
        hpk.x = f2bf(v.x); lpk.x = f2bf(v.x - bf2f(hpk.x));
        hpk.y = f2bf(v.y); lpk.y = f2bf(v.y - bf2f(hpk.y));
        hpk.z = f2bf(v.z); lpk.z = f2bf(v.z - bf2f(hpk.z));
        hpk.w = f2bf(v.w); lpk.w = f2bf(v.w - bf2f(hpk.w));
        *reinterpret_cast<ushort4*>(xhr + i4) = hpk;
        *reinterpret_cast<ushort4*>(xlr + i4) = lpk;
        loc += (v.x + v.y) + (v.z + v.w);
    }
    __shared__ float red[256];
    red[tid] = loc;
    __syncthreads();
    for (int st = 128; st > 0; st >>= 1) {
        if (tid < st) red[tid] += red[tid + st];
        __syncthreads();
    }
    if (tid == 0) s[row] = red[0];
}

// ---------------- K2: partG[b][kc] += X_tile X_tile^T over K-chunk (split-bf16, 3 passes)
__global__ __launch_bounds__(256) void gram(
        const unsigned short* __restrict__ xh, const unsigned short* __restrict__ xl,
        float* __restrict__ partG) {
    const int tile = blockIdx.x;   // 0..3 -> (mt,nt)
    const int kc   = blockIdx.y;   // 0..15 (K-chunk of 1024)
    const int b    = blockIdx.z;
    const int m0 = (tile >> 1) * 128, n0 = (tile & 1) * 128;
    __shared__ __align__(16) unsigned short Ah[128 * 40];
    __shared__ __align__(16) unsigned short Al[128 * 40];
    __shared__ __align__(16) unsigned short Bh[128 * 40];
    __shared__ __align__(16) unsigned short Bl[128 * 40];
    const int tid = threadIdx.x, lane = tid & 63, wid = tid >> 6;
    const int wm = (wid >> 1) * 64, wn = (wid & 1) * 64;
    const int l15 = lane & 15, lg = lane >> 4;
    const size_t xbase = (size_t)b * 256 * HW;
    const int r = tid >> 3, c4 = (tid & 7) * 4;
    f32x4 acc[4][4] = {};

    for (int ks = 0; ks < 32; ++ks) {
        const int k0 = kc * 1024 + ks * 32;
        #pragma unroll
        for (int p = 0; p < 4; ++p) {
            const int row = r + p * 32;
            const size_t offA = xbase + (size_t)(m0 + row) * HW + k0 + c4;
            const size_t offB = xbase + (size_t)(n0 + row) * HW + k0 + c4;
            *reinterpret_cast<ushort4*>(&Ah[row * 40 + c4]) = *reinterpret_cast<const ushort4*>(xh + offA);
            *reinterpret_cast<ushort4*>(&Al[row * 40 + c4]) = *reinterpret_cast<const ushort4*>(xl + offA);
            *reinterpret_cast<ushort4*>(&Bh[row * 40 + c4]) = *reinterpret_cast<const ushort4*>(xh + offB);
            *reinterpret_cast<ushort4*>(&Bl[row * 40 + c4]) = *reinterpret_cast<const ushort4*>(xl + offB);
        }
        __syncthreads();
        bf16x8 fah[4], fal[4], fbh[4], fbl[4];
        #pragma unroll
        for (int i = 0; i < 4; ++i) {
            const int rowA = (wm + i * 16 + l15) * 40 + lg * 8;
            fah[i] = *reinterpret_cast<const bf16x8*>(&Ah[rowA]);
            fal[i] = *reinterpret_cast<const bf16x8*>(&Al[rowA]);
        }
        #pragma unroll
        for (int j = 0; j < 4; ++j) {
            const int rowB = (wn + j * 16 + l15) * 40 + lg * 8;
            fbh[j] = *reinterpret_cast<const bf16x8*>(&Bh[rowB]);
            fbl[j] = *reinterpret_cast<const bf16x8*>(&Bl[rowB]);
        }
        #pragma unroll
        for (int i = 0; i < 4; ++i)
            #pragma unroll
            for (int j = 0; j < 4; ++j) {
                acc[i][j] = __builtin_amdgcn_mfma_f32_16x16x32_bf16(fah[i], fbh[j], acc[i][j], 0, 0, 0);
                acc[i][j] = __builtin_amdgcn_mfma_f32_16x16x32_bf16(fah[i], fbl[j], acc[i][j], 0, 0, 0);
                acc[i][j] = __builtin_amdgcn_mfma_f32_16x16x32_bf16(fal[i], fbh[j], acc[i][j], 0, 0, 0);
            }
        __syncthreads();
    }
    float* pw = partG + (size_t)(b * 16 + kc) * 65536;
    #pragma unroll
    for (int i = 0; i < 4; ++i)
        #pragma unroll
        for (int rr = 0; rr < 4; ++rr) {
            const int m = m0 + wm + i * 16 + lg * 4 + rr;
            #pragma unroll
            for (int j = 0; j < 4; ++j)
                pw[m * 256 + n0 + wn + j * 16 + l15] = acc[i][j][rr];
        }
}

// ---------------- K3: G = sum over 16 chunks of partG
__global__ __launch_bounds__(256) void greduce(
        const float* __restrict__ partG, float* __restrict__ G) {
    const size_t idx = (size_t)blockIdx.x * 256 + threadIdx.x;  // 524288
    const int b = (int)(idx >> 16);
    const int i = (int)(idx & 65535);
    float sacc = 0.f;
    #pragma unroll
    for (int kc = 0; kc < 16; ++kc)
        sacc += partG[(size_t)(b * 16 + kc) * 65536 + i];
    G[idx] = sacc;
}

// ---------------- K4a: T[b] = Wq_all (256x256) @ G[b] (256x256), fp32 tiled GEMM
__global__ __launch_bounds__(256) void tgemm(
        const float* __restrict__ G, const float* __restrict__ Wqkv,
        float* __restrict__ T) {
    const int c0 = blockIdx.x * 64;   // c' tile
    const int d0 = blockIdx.y * 64;   // d tile
    const int b  = blockIdx.z;
    __shared__ float Ws[64][68];
    __shared__ float Gs[64][68];
    const int tid = threadIdx.x;
    const float* Gb = G + (size_t)b * 65536;
    const int ry = (tid >> 4) * 4, cx = (tid & 15) * 4;
    const int r = tid >> 2, q = (tid & 3) * 16;
    float acc[4][4] = {};

    for (int cb = 0; cb < 4; ++cb) {
        __syncthreads();
        #pragma unroll
        for (int j = 0; j < 16; j += 4) {
            *reinterpret_cast<float4*>(&Ws[r][q + j]) =
                *reinterpret_cast<const float4*>(Wqkv + (size_t)(d0 + r) * 256 + cb * 64 + q + j);
            *reinterpret_cast<float4*>(&Gs[r][q + j]) =
                *reinterpret_cast<const float4*>(Gb + (size_t)(cb * 64 + r) * 256 + c0 + q + j);
        }
        __syncthreads();
        #pragma unroll 8
        for (int k = 0; k < 64; ++k) {
            const float4 g4 = *reinterpret_cast<const float4*>(&Gs[k][cx]);
            #pragma unroll
            for (int i = 0; i < 4; ++i) {
                const float a = Ws[ry + i][k];
                acc[i][0] += a * g4.x;
                acc[i][1] += a * g4.y;
                acc[i][2] += a * g4.z;
                acc[i][3] += a * g4.w;
            }
        }
    }
    float* Tb = T + (size_t)b * 65536;
    #pragma unroll
    for (int i = 0; i < 4; ++i)
        #pragma unroll
        for (int j = 0; j < 4; ++j)
            Tb[(size_t)(d0 + ry + i) * 256 + c0 + cx + j] = acc[i][j];
}

// ---------------- K4b: per (b,h): logits = T_h Wk_h^T + bias; softmax -> attn
__global__ __launch_bounds__(256) void logits_sm(
        const float* __restrict__ T, const float* __restrict__ Wqkv,
        const float* __restrict__ bqkv, const float* __restrict__ s,
        float* __restrict__ attn) {
    const int bh = blockIdx.x, b = bh >> 2, h = bh & 3;
    const int tid = threadIdx.x;
    __shared__ float Ts[64][257];   // T rows for this head
    __shared__ float Wks[64][257];  // Wk rows for this head
    __shared__ float lgs[64][65];
    __shared__ float qs[64], ks[64];
    const float* Tb = T + (size_t)b * 65536 + (size_t)(h * 64) * 256;
    const float* Wq = Wqkv + (size_t)(h * 64) * 256;
    const float* Wk = Wqkv + (size_t)(256 + h * 64) * 256;

    {   // stage Ts, Wks: thread loads 64 floats of row r starting col q
        const int r = tid >> 2, q = (tid & 3) * 64;
        #pragma unroll
        for (int j = 0; j < 64; j += 4) {
            const float4 t4 = *reinterpret_cast<const float4*>(Tb + (size_t)r * 256 + q + j);
            Ts[r][q + j + 0] = t4.x; Ts[r][q + j + 1] = t4.y;
            Ts[r][q + j + 2] = t4.z; Ts[r][q + j + 3] = t4.w;
            const float4 w4 = *reinterpret_cast<const float4*>(Wk + (size_t)r * 256 + q + j);
            Wks[r][q + j + 0] = w4.x; Wks[r][q + j + 1] = w4.y;
            Wks[r][q + j + 2] = w4.z; Wks[r][q + j + 3] = w4.w;
        }
    }
    if (tid < 128) {   // qs = Wq s_b, ks = Wk s_b (bias path)
        const int d = tid & 63;
        const float* wr = (tid < 64) ? (Wq + (size_t)d * 256) : (Wk + (size_t)d * 256);
        const float* sb = s + b * 256;
        float a = 0.f;
        for (int c = 0; c < 256; ++c) a += wr[c] * sb[c];
        if (tid < 64) qs[d] = a; else ks[d] = a;
    }
    __syncthreads();

    const int d4 = (tid >> 4) * 4, e4 = (tid & 15) * 4;
    float acc[4][4] = {};
    #pragma unroll 4
    for (int c = 0; c < 256; ++c) {
        float tv[4], wv[4];
        #pragma unroll
        for (int i = 0; i < 4; ++i) tv[i] = Ts[d4 + i][c];
        #pragma unroll
        for (int j = 0; j < 4; ++j) wv[j] = Wks[e4 + j][c];
        #pragma unroll
        for (int i = 0; i < 4; ++i)
            #pragma unroll
            for (int j = 0; j < 4; ++j)
                acc[i][j] += tv[i] * wv[j];
    }
    const float* bq = bqkv + h * 64;
    const float* bk = bqkv + 256 + h * 64;
    #pragma unroll
    for (int i = 0; i < 4; ++i) {
        const float bqi = bq[d4 + i], qsi = qs[d4 + i];
        #pragma unroll
        for (int j = 0; j < 4; ++j) {
            const int e = e4 + j;
            lgs[d4 + i][e] = SCALE_F * (acc[i][j] + bqi * ks[e] + bk[e] * qsi + NF * bqi * bk[e]);
        }
    }
    __syncthreads();
    if (tid < 64) {
        float m = -1e30f;
        for (int e = 0; e < 64; ++e) m = fmaxf(m, lgs[tid][e]);
        float sum = 0.f;
        for (int e = 0; e < 64; ++e) {
            const float ex = __expf(lgs[tid][e] - m);
            sum += ex;
            lgs[tid][e] = ex;
        }
        const float inv = 1.f / sum;
        float* ar = attn + ((size_t)bh * 64 + tid) * 64;
        for (int e = 0; e < 64; ++e) ar[e] = lgs[tid][e] * inv;
    }
}

// ---------------- K5: M[b][o][h*64+e] = sum_d Wproj[o][h*64+d] attn[b,h,d,e] (fp32)
__global__ __launch_bounds__(256) void build_M(
        const float* __restrict__ attn, const float* __restrict__ Wproj,
        float* __restrict__ M) {
    const int g = blockIdx.x * 256 + threadIdx.x;
    const int b = g >> 16, o = (g >> 8) & 255, cpx = g & 255;
    const int h = cpx >> 6, e = cpx & 63;
    const float* wrow = Wproj + (size_t)o * 256 + h * 64;
    const float* acol = attn + ((size_t)(b * 4 + h) * 64) * 64 + e;
    float sacc = 0.f;
    #pragma unroll
    for (int d = 0; d < 64; ++d) sacc += wrow[d] * acol[d * 64];
    M[g] = sacc;
}

// ---------------- K6: P[b] = M[b] Wv (bf16); cvec[b] = M[b] bv + bproj
__global__ __launch_bounds__(256) void build_P(
        const float* __restrict__ M, const float* __restrict__ Wqkv,
        const float* __restrict__ bqkv, const float* __restrict__ bproj,
        unsigned short* __restrict__ P, float* __restrict__ cvec) {
    const int b = blockIdx.x >> 4, oc = blockIdx.x & 15;   // 16 o-rows per block
    const int tid = threadIdx.x, c = tid;
    __shared__ float Wvs[32 * 256];
    __shared__ float Ms[16 * 256];
    for (int j = tid; j < 16 * 256; j += 256)
        Ms[j] = M[(size_t)b * 65536 + oc * 16 * 256 + j];
    float acc[16];
    #pragma unroll
    for (int o = 0; o < 16; ++o) acc[o] = 0.f;
    for (int cb2 = 0; cb2 < 8; ++cb2) {
        __syncthreads();
        for (int j = tid; j < 32 * 256; j += 256)
            Wvs[j] = Wqkv[(size_t)(512 + cb2 * 32) * 256 + j];
        __syncthreads();
        for (int c2 = 0; c2 < 32; ++c2) {
            const float wv = Wvs[c2 * 256 + c];
            #pragma unroll
            for (int o = 0; o < 16; ++o)
                acc[o] += Ms[o * 256 + cb2 * 32 + c2] * wv;
        }
    }
    #pragma unroll
    for (int o = 0; o < 16; ++o)
        P[(size_t)b * 65536 + (size_t)(oc * 16 + o) * 256 + c] = f2bf(acc[o]);
    if (tid < 16) {
        const int o = oc * 16 + tid;
        float a = bproj[o];
        for (int c2 = 0; c2 < 256; ++c2)
            a += M[(size_t)b * 65536 + (size_t)o * 256 + c2] * bqkv[512 + c2];
        cvec[b * 256 + o] = a;
    }
}

// ---------------- K7: out[b][o][n] = sum_c P[b][o][c] x_hi[b][c][n] + cvec[b][o]
__global__ __launch_bounds__(256) void out_gemm(
        const unsigned short* __restrict__ P, const unsigned short* __restrict__ xh,
        const float* __restrict__ cvec, float* __restrict__ out) {
    const int n0 = blockIdx.x * 128;
    const int m0 = blockIdx.y * 128;
    const int b  = blockIdx.z;
    __shared__ __align__(16) unsigned short As[128 * 40];
    __shared__ __align__(16) unsigned short Bs[128 * 40];
    const int tid = threadIdx.x, lane = tid & 63, wid = tid >> 6;
    const int wm = (wid >> 1) * 64, wn = (wid & 1) * 64;
    const int l15 = lane & 15, lg = lane >> 4;
    const unsigned short* Pb = P + (size_t)b * 65536;
    const unsigned short* xb = xh + (size_t)b * 256 * HW;
    f32x4 acc[4][4] = {};

    for (int k0 = 0; k0 < 256; k0 += 32) {
        {
            const int r = tid >> 3, c4 = (tid & 7) * 4;
            #pragma unroll
            for (int p = 0; p < 4; ++p) {
                const int row = r + p * 32;
                *reinterpret_cast<ushort4*>(&As[row * 40 + c4]) =
                    *reinterpret_cast<const ushort4*>(Pb + (size_t)(m0 + row) * 256 + k0 + c4);
            }
        }
        {
            const int n = tid & 127, kq = (tid >> 7) * 4;
            #pragma unroll
            for (int p = 0; p < 4; ++p) {
                const int kk = p * 8 + kq;
                ushort4 pk;
                pk.x = xb[(size_t)(k0 + kk + 0) * HW + n0 + n];
                pk.y = xb[(size_t)(k0 + kk + 1) * HW + n0 + n];
                pk.z = xb[(size_t)(k0 + kk + 2) * HW + n0 + n];
                pk.w = xb[(size_t)(k0 + kk + 3) * HW + n0 + n];
                *reinterpret_cast<ushort4*>(&Bs[n * 40 + kk]) = pk;
            }
        }
        __syncthreads();
        bf16x8 fa[4], fb[4];
        #pragma unroll
        for (int i = 0; i < 4; ++i)
            fa[i] = *reinterpret_cast<const bf16x8*>(&As[(wm + i * 16 + l15) * 40 + lg * 8]);
        #pragma unroll
        for (int j = 0; j < 4; ++j)
            fb[j] = *reinterpret_cast<const bf16x8*>(&Bs[(wn + j * 16 + l15) * 40 + lg * 8]);
        #pragma unroll
        for (int i = 0; i < 4; ++i)
            #pragma unroll
            for (int j = 0; j < 4; ++j)
                acc[i][j] = __builtin_amdgcn_mfma_f32_16x16x32_bf16(fa[i], fb[j], acc[i][j], 0, 0, 0);
        __syncthreads();
    }
    float* ob = out + (size_t)b * 256 * HW;
    #pragma unroll
    for (int i = 0; i < 4; ++i)
        #pragma unroll
        for (int rr = 0; rr < 4; ++rr) {
            const int m = m0 + wm + i * 16 + lg * 4 + rr;
            const float bp = cvec[b * 256 + m];
            #pragma unroll
            for (int j = 0; j < 4; ++j) {
                const int n = n0 + wn + j * 16 + l15;
                ob[(size_t)m * HW + n] = acc[i][rr ? j : j][rr] + bp;  // (kept simple below)
            }
        }
}

extern "C" void kernel_launch(void* const* d_in, const int* in_sizes, int n_in,
                              void* d_out, int out_size, void* d_ws, size_t ws_size,
                              hipStream_t stream) {
    const float* x     = (const float*)d_in[0];
    const float* Wqkv  = (const float*)d_in[1];
    const float* bqkv  = (const float*)d_in[2];
    const float* Wproj = (const float*)d_in[3];
    const float* bproj = (const float*)d_in[4];
    float* out = (float*)d_out;

    // ws layout (bytes):
    //   x_hi  :         0  67108864
    //   x_lo  :  67108864  67108864
    //   partG : 134217728  33554432   (8*16*256*256 f32)
    //   G     : 167772160   2097152
    //   attn  : 169869312    524288
    //   M     : 170393600   2097152
    //   P     : 172490752   1048576
    //   cvec  : 173539328      8192
    //   s     : 173547520      8192
    //   T     : 173555712   2097152   -> total ~167.5 MiB
    char* ws = (char*)d_ws;
    unsigned short* xh = (unsigned short*)(ws);
    unsigned short* xl = (unsigned short*)(ws + 67108864);
    float* partG = (float*)(ws + 134217728);
    float* G     = (float*)(ws + 167772160);
    float* attn  = (float*)(ws + 169869312);
    float* M     = (float*)(ws + 170393600);
    unsigned short* P = (unsigned short*)(ws + 172490752);
    float* cvec  = (float*)(ws + 173539328);
    float* s     = (float*)(ws + 173547520);
    float* T     = (float*)(ws + 173555712);

    cast_x   <<<2048,            256, 0, stream>>>(x, xh, xl, s);
    gram     <<<dim3(4, 16, 8),  256, 0, stream>>>(xh, xl, partG);
    greduce  <<<2048,            256, 0, stream>>>(partG, G);
    tgemm    <<<dim3(4, 4, 8),   256, 0, stream>>>(G, Wqkv, T);
    logits_sm<<<32,              256, 0, stream>>>(T, Wqkv, bqkv, s, attn);
    build_M  <<<2048,            256, 0, stream>>>(attn, Wproj, M);
    build_P  <<<128,             256, 0, stream>>>(M, Wqkv, bqkv, bproj, P, cvec);
    out_gemm <<<dim3(128, 2, 8), 256, 0, stream>>>(P, xh, cvec, out);
}

// Round 4
// 262.630 us; speedup vs baseline: 1.4743x; 1.1138x over previous
//
#include <hip/hip_runtime.h>
#include <hip/hip_bf16.h>
#include <stdint.h>

// B=8, C=256, HW=16384, HEADS=4, HEAD_DIM=64, SCALE=1/8.
// Restructure: G[b]=x x^T (split-bf16 MFMA, fp32-accurate);
// T[b] = Wq_all G[b]; logits = T_h Wk_h^T (+bias terms); attn = softmax;
// M = Wproj blockdiag(attn); P = M Wv; out = P x + (M bv + bproj).

#define HW 16384
#define SCALE_F 0.125f
#define NF 16384.0f

typedef __attribute__((ext_vector_type(8))) short bf16x8;
typedef __attribute__((ext_vector_type(4))) float f32x4;

__device__ __forceinline__ unsigned short f2bf(float f) {
    union { float f; uint32_t u; } v; v.f = f;
    uint32_t u = v.u;
    return (unsigned short)((u + 0x7fffu + ((u >> 16) & 1u)) >> 16);  // RNE
}
__device__ __forceinline__ float bf2f(unsigned short s) {
    union { uint32_t u; float f; } v; v.u = ((uint32_t)s) << 16;
    return v.f;
}
__device__ __forceinline__ void gload16(const void* g, void* l) {
    __builtin_amdgcn_global_load_lds(
        (const __attribute__((address_space(1))) unsigned int*)g,
        (__attribute__((address_space(3))) unsigned int*)l, 16, 0, 0);
}

// ---------------- K1: cast x -> x_hi, x_lo (bf16) + row sums s[b*256+c]
__global__ __launch_bounds__(256) void cast_x(
        const float* __restrict__ x, unsigned short* __restrict__ xh,
        unsigned short* __restrict__ xl, float* __restrict__ s) {
    const int row = blockIdx.x;          // b*256+c, 2048 rows
    const int tid = threadIdx.x;
    const float* xr = x + (size_t)row * HW;
    unsigned short* xhr = xh + (size_t)row * HW;
    unsigned short* xlr = xl + (size_t)row * HW;
    float loc = 0.f;
    #pragma unroll
    for (int p = 0; p < 16; ++p) {
        const int i4 = (p * 256 + tid) * 4;
        const float4 v = *reinterpret_cast<const float4*>(xr + i4);
        ushort4 hpk, lpk;
        hpk.x = f2bf(v.x); lpk.x = f2bf(v.x - bf2f(hpk.x));
        hpk.y = f2bf(v.y); lpk.y = f2bf(v.y - bf2f(hpk.y));
        hpk.z = f2bf(v.z); lpk.z = f2bf(v.z - bf2f(hpk.z));
        hpk.w = f2bf(v.w); lpk.w = f2bf(v.w - bf2f(hpk.w));
        *reinterpret_cast<ushort4*>(xhr + i4) = hpk;
        *reinterpret_cast<ushort4*>(xlr + i4) = lpk;
        loc += (v.x + v.y) + (v.z + v.w);
    }
    __shared__ float red[256];
    red[tid] = loc;
    __syncthreads();
    for (int st = 128; st > 0; st >>= 1) {
        if (tid < st) red[tid] += red[tid + st];
        __syncthreads();
    }
    if (tid == 0) s[row] = red[0];
}

// ---------------- K2 v2: one 256x256 Gram tile per (kc,b); global_load_lds + swizzle + dbuf
__global__ __launch_bounds__(512, 2) void gram(
        const unsigned short* __restrict__ xh, const unsigned short* __restrict__ xl,
        float* __restrict__ partG) {
    const int kc = blockIdx.x;    // 0..31, K-chunk of 512
    const int b  = blockIdx.y;
    __shared__ __align__(16) unsigned short Hs[2][256 * 32];
    __shared__ __align__(16) unsigned short Ls[2][256 * 32];
    const int tid = threadIdx.x, lane = tid & 63, w = tid >> 6;
    const int l15 = lane & 15, lg = lane >> 4;
    const int wr = w >> 1, wc = w & 1;          // 4x64-row x 2x128-col wave grid
    const int lr = lane >> 2, lq = lane & 3;    // staging: row-in-16, 16B slot
    const size_t xbase = (size_t)b * 256 * HW;
    f32x4 acc[4][8] = {};

    const int k0base = kc * 512;
    // stage: wave w stages rows [w*32,(w+1)*32) of H and L for one 32-K step.
    // LDS linear [row][32 bf16]; global source pre-swizzled so that swizzled
    // ds_read (byte ^ ((row>>1)&3)<<4) returns the true fragment (rule 21).
#define STAGE(sel, k0)                                                          \
    {                                                                           \
        _Pragma("unroll")                                                       \
        for (int p = 0; p < 2; ++p) {                                           \
            const int rloc = w * 32 + p * 16 + lr;                              \
            const int cb = ((lq ^ ((rloc >> 1) & 3)) << 4);                     \
            const size_t ge = xbase + (size_t)rloc * HW + (k0);                 \
            gload16((const char*)(xh + ge) + cb, &Hs[sel][(w * 32 + p * 16) * 32]); \
            gload16((const char*)(xl + ge) + cb, &Ls[sel][(w * 32 + p * 16) * 32]); \
        }                                                                       \
    }

    STAGE(0, k0base);
    __syncthreads();
    for (int t = 0; t < 16; ++t) {
        if (t < 15) STAGE((t + 1) & 1, k0base + (t + 1) * 32);
        const int sel = t & 1;
        bf16x8 fah[4], fal[4];
        #pragma unroll
        for (int i = 0; i < 4; ++i) {
            const int row = wr * 64 + i * 16 + l15;
            const int off = row * 64 + ((lg ^ ((row >> 1) & 3)) << 4);
            fah[i] = *reinterpret_cast<const bf16x8*>((const char*)&Hs[sel][0] + off);
            fal[i] = *reinterpret_cast<const bf16x8*>((const char*)&Ls[sel][0] + off);
        }
        #pragma unroll
        for (int j = 0; j < 8; ++j) {
            const int row = wc * 128 + j * 16 + l15;
            const int off = row * 64 + ((lg ^ ((row >> 1) & 3)) << 4);
            const bf16x8 fbh = *reinterpret_cast<const bf16x8*>((const char*)&Hs[sel][0] + off);
            const bf16x8 fbl = *reinterpret_cast<const bf16x8*>((const char*)&Ls[sel][0] + off);
            #pragma unroll
            for (int i = 0; i < 4; ++i) {
                acc[i][j] = __builtin_amdgcn_mfma_f32_16x16x32_bf16(fah[i], fbh, acc[i][j], 0, 0, 0);
                acc[i][j] = __builtin_amdgcn_mfma_f32_16x16x32_bf16(fah[i], fbl, acc[i][j], 0, 0, 0);
                acc[i][j] = __builtin_amdgcn_mfma_f32_16x16x32_bf16(fal[i], fbh, acc[i][j], 0, 0, 0);
            }
        }
        __syncthreads();
    }
#undef STAGE
    float* pw = partG + (size_t)(b * 32 + kc) * 65536;
    #pragma unroll
    for (int i = 0; i < 4; ++i)
        #pragma unroll
        for (int rr = 0; rr < 4; ++rr) {
            const int m = wr * 64 + i * 16 + lg * 4 + rr;
            #pragma unroll
            for (int j = 0; j < 8; ++j)
                pw[m * 256 + wc * 128 + j * 16 + l15] = acc[i][j][rr];
        }
}

// ---------------- K3: G = sum over 32 chunks of partG
__global__ __launch_bounds__(256) void greduce(
        const float* __restrict__ partG, float* __restrict__ G) {
    const size_t idx = (size_t)blockIdx.x * 256 + threadIdx.x;  // 524288
    const int b = (int)(idx >> 16);
    const int i = (int)(idx & 65535);
    float sacc = 0.f;
    #pragma unroll
    for (int kc = 0; kc < 32; ++kc)
        sacc += partG[(size_t)(b * 32 + kc) * 65536 + i];
    G[idx] = sacc;
}

// ---------------- K4a: T[b] = Wq_all (256x256) @ G[b] (256x256), fp32 tiled GEMM
__global__ __launch_bounds__(256) void tgemm(
        const float* __restrict__ G, const float* __restrict__ Wqkv,
        float* __restrict__ T) {
    const int c0 = blockIdx.x * 64;   // c' tile
    const int d0 = blockIdx.y * 64;   // d tile
    const int b  = blockIdx.z;
    __shared__ float Ws[64][68];
    __shared__ float Gs[64][68];
    const int tid = threadIdx.x;
    const float* Gb = G + (size_t)b * 65536;
    const int ry = (tid >> 4) * 4, cx = (tid & 15) * 4;
    const int r = tid >> 2, q = (tid & 3) * 16;
    float acc[4][4] = {};

    for (int cb = 0; cb < 4; ++cb) {
        __syncthreads();
        #pragma unroll
        for (int j = 0; j < 16; j += 4) {
            *reinterpret_cast<float4*>(&Ws[r][q + j]) =
                *reinterpret_cast<const float4*>(Wqkv + (size_t)(d0 + r) * 256 + cb * 64 + q + j);
            *reinterpret_cast<float4*>(&Gs[r][q + j]) =
                *reinterpret_cast<const float4*>(Gb + (size_t)(cb * 64 + r) * 256 + c0 + q + j);
        }
        __syncthreads();
        #pragma unroll 8
        for (int k = 0; k < 64; ++k) {
            const float4 g4 = *reinterpret_cast<const float4*>(&Gs[k][cx]);
            #pragma unroll
            for (int i = 0; i < 4; ++i) {
                const float a = Ws[ry + i][k];
                acc[i][0] += a * g4.x;
                acc[i][1] += a * g4.y;
                acc[i][2] += a * g4.z;
                acc[i][3] += a * g4.w;
            }
        }
    }
    float* Tb = T + (size_t)b * 65536;
    #pragma unroll
    for (int i = 0; i < 4; ++i)
        #pragma unroll
        for (int j = 0; j < 4; ++j)
            Tb[(size_t)(d0 + ry + i) * 256 + c0 + cx + j] = acc[i][j];
}

// ---------------- K4b: per (b,h): logits = T_h Wk_h^T + bias; softmax -> attn
__global__ __launch_bounds__(256) void logits_sm(
        const float* __restrict__ T, const float* __restrict__ Wqkv,
        const float* __restrict__ bqkv, const float* __restrict__ s,
        float* __restrict__ attn) {
    const int bh = blockIdx.x, b = bh >> 2, h = bh & 3;
    const int tid = threadIdx.x;
    __shared__ float Ts[64][257];   // T rows for this head
    __shared__ float Wks[64][257];  // Wk rows for this head
    __shared__ float lgs[64][65];
    __shared__ float qs[64], ks[64];
    const float* Tb = T + (size_t)b * 65536 + (size_t)(h * 64) * 256;
    const float* Wq = Wqkv + (size_t)(h * 64) * 256;
    const float* Wk = Wqkv + (size_t)(256 + h * 64) * 256;

    {   // stage Ts, Wks
        const int r = tid >> 2, q = (tid & 3) * 64;
        #pragma unroll
        for (int j = 0; j < 64; j += 4) {
            const float4 t4 = *reinterpret_cast<const float4*>(Tb + (size_t)r * 256 + q + j);
            Ts[r][q + j + 0] = t4.x; Ts[r][q + j + 1] = t4.y;
            Ts[r][q + j + 2] = t4.z; Ts[r][q + j + 3] = t4.w;
            const float4 w4 = *reinterpret_cast<const float4*>(Wk + (size_t)r * 256 + q + j);
            Wks[r][q + j + 0] = w4.x; Wks[r][q + j + 1] = w4.y;
            Wks[r][q + j + 2] = w4.z; Wks[r][q + j + 3] = w4.w;
        }
    }
    if (tid < 128) {   // qs = Wq s_b, ks = Wk s_b (bias path)
        const int d = tid & 63;
        const float* wr = (tid < 64) ? (Wq + (size_t)d * 256) : (Wk + (size_t)d * 256);
        const float* sb = s + b * 256;
        float a = 0.f;
        for (int c = 0; c < 256; ++c) a += wr[c] * sb[c];
        if (tid < 64) qs[d] = a; else ks[d] = a;
    }
    __syncthreads();

    const int d4 = (tid >> 4) * 4, e4 = (tid & 15) * 4;
    float acc[4][4] = {};
    #pragma unroll 4
    for (int c = 0; c < 256; ++c) {
        float tv[4], wv[4];
        #pragma unroll
        for (int i = 0; i < 4; ++i) tv[i] = Ts[d4 + i][c];
        #pragma unroll
        for (int j = 0; j < 4; ++j) wv[j] = Wks[e4 + j][c];
        #pragma unroll
        for (int i = 0; i < 4; ++i)
            #pragma unroll
            for (int j = 0; j < 4; ++j)
                acc[i][j] += tv[i] * wv[j];
    }
    const float* bq = bqkv + h * 64;
    const float* bk = bqkv + 256 + h * 64;
    #pragma unroll
    for (int i = 0; i < 4; ++i) {
        const float bqi = bq[d4 + i], qsi = qs[d4 + i];
        #pragma unroll
        for (int j = 0; j < 4; ++j) {
            const int e = e4 + j;
            lgs[d4 + i][e] = SCALE_F * (acc[i][j] + bqi * ks[e] + bk[e] * qsi + NF * bqi * bk[e]);
        }
    }
    __syncthreads();
    if (tid < 64) {
        float m = -1e30f;
        for (int e = 0; e < 64; ++e) m = fmaxf(m, lgs[tid][e]);
        float sum = 0.f;
        for (int e = 0; e < 64; ++e) {
            const float ex = __expf(lgs[tid][e] - m);
            sum += ex;
            lgs[tid][e] = ex;
        }
        const float inv = 1.f / sum;
        float* ar = attn + ((size_t)bh * 64 + tid) * 64;
        for (int e = 0; e < 64; ++e) ar[e] = lgs[tid][e] * inv;
    }
}

// ---------------- K5: M[b][o][h*64+e] = sum_d Wproj[o][h*64+d] attn[b,h,d,e] (fp32)
__global__ __launch_bounds__(256) void build_M(
        const float* __restrict__ attn, const float* __restrict__ Wproj,
        float* __restrict__ M) {
    const int g = blockIdx.x * 256 + threadIdx.x;
    const int b = g >> 16, o = (g >> 8) & 255, cpx = g & 255;
    const int h = cpx >> 6, e = cpx & 63;
    const float* wrow = Wproj + (size_t)o * 256 + h * 64;
    const float* acol = attn + ((size_t)(b * 4 + h) * 64) * 64 + e;
    float sacc = 0.f;
    #pragma unroll
    for (int d = 0; d < 64; ++d) sacc += wrow[d] * acol[d * 64];
    M[g] = sacc;
}

// ---------------- K6: P[b] = M[b] Wv (bf16); cvec[b] = M[b] bv + bproj
__global__ __launch_bounds__(256) void build_P(
        const float* __restrict__ M, const float* __restrict__ Wqkv,
        const float* __restrict__ bqkv, const float* __restrict__ bproj,
        unsigned short* __restrict__ P, float* __restrict__ cvec) {
    const int b = blockIdx.x >> 4, oc = blockIdx.x & 15;   // 16 o-rows per block
    const int tid = threadIdx.x, c = tid;
    __shared__ float Wvs[32 * 256];
    __shared__ float Ms[16 * 256];
    for (int j = tid; j < 16 * 256; j += 256)
        Ms[j] = M[(size_t)b * 65536 + oc * 16 * 256 + j];
    float acc[16];
    #pragma unroll
    for (int o = 0; o < 16; ++o) acc[o] = 0.f;
    for (int cb2 = 0; cb2 < 8; ++cb2) {
        __syncthreads();
        for (int j = tid; j < 32 * 256; j += 256)
            Wvs[j] = Wqkv[(size_t)(512 + cb2 * 32) * 256 + j];
        __syncthreads();
        for (int c2 = 0; c2 < 32; ++c2) {
            const float wv = Wvs[c2 * 256 + c];
            #pragma unroll
            for (int o = 0; o < 16; ++o)
                acc[o] += Ms[o * 256 + cb2 * 32 + c2] * wv;
        }
    }
    #pragma unroll
    for (int o = 0; o < 16; ++o)
        P[(size_t)b * 65536 + (size_t)(oc * 16 + o) * 256 + c] = f2bf(acc[o]);
    if (tid < 16) {
        const int o = oc * 16 + tid;
        float a = bproj[o];
        for (int c2 = 0; c2 < 256; ++c2)
            a += M[(size_t)b * 65536 + (size_t)o * 256 + c2] * bqkv[512 + c2];
        cvec[b * 256 + o] = a;
    }
}

// ---------------- K7: out[b][o][n] = sum_c P[b][o][c] x_hi[b][c][n] + cvec[b][o]
__global__ __launch_bounds__(256) void out_gemm(
        const unsigned short* __restrict__ P, const unsigned short* __restrict__ xh,
        const float* __restrict__ cvec, float* __restrict__ out) {
    const int n0 = blockIdx.x * 128;
    const int m0 = blockIdx.y * 128;
    const int b  = blockIdx.z;
    __shared__ __align__(16) unsigned short As[128 * 40];
    __shared__ __align__(16) unsigned short Bs[128 * 40];
    const int tid = threadIdx.x, lane = tid & 63, wid = tid >> 6;
    const int wm = (wid >> 1) * 64, wn = (wid & 1) * 64;
    const int l15 = lane & 15, lg = lane >> 4;
    const unsigned short* Pb = P + (size_t)b * 65536;
    const unsigned short* xb = xh + (size_t)b * 256 * HW;
    f32x4 acc[4][4] = {};

    for (int k0 = 0; k0 < 256; k0 += 32) {
        {
            const int r = tid >> 3, c4 = (tid & 7) * 4;
            #pragma unroll
            for (int p = 0; p < 4; ++p) {
                const int row = r + p * 32;
                *reinterpret_cast<ushort4*>(&As[row * 40 + c4]) =
                    *reinterpret_cast<const ushort4*>(Pb + (size_t)(m0 + row) * 256 + k0 + c4);
            }
        }
        {
            const int n = tid & 127, kq = (tid >> 7) * 4;
            #pragma unroll
            for (int p = 0; p < 4; ++p) {
                const int kk = p * 8 + kq;
                ushort4 pk;
                pk.x = xb[(size_t)(k0 + kk + 0) * HW + n0 + n];
                pk.y = xb[(size_t)(k0 + kk + 1) * HW + n0 + n];
                pk.z = xb[(size_t)(k0 + kk + 2) * HW + n0 + n];
                pk.w = xb[(size_t)(k0 + kk + 3) * HW + n0 + n];
                *reinterpret_cast<ushort4*>(&Bs[n * 40 + kk]) = pk;
            }
        }
        __syncthreads();
        bf16x8 fa[4], fb[4];
        #pragma unroll
        for (int i = 0; i < 4; ++i)
            fa[i] = *reinterpret_cast<const bf16x8*>(&As[(wm + i * 16 + l15) * 40 + lg * 8]);
        #pragma unroll
        for (int j = 0; j < 4; ++j)
            fb[j] = *reinterpret_cast<const bf16x8*>(&Bs[(wn + j * 16 + l15) * 40 + lg * 8]);
        #pragma unroll
        for (int i = 0; i < 4; ++i)
            #pragma unroll
            for (int j = 0; j < 4; ++j)
                acc[i][j] = __builtin_amdgcn_mfma_f32_16x16x32_bf16(fa[i], fb[j], acc[i][j], 0, 0, 0);
        __syncthreads();
    }
    float* ob = out + (size_t)b * 256 * HW;
    #pragma unroll
    for (int i = 0; i < 4; ++i)
        #pragma unroll
        for (int rr = 0; rr < 4; ++rr) {
            const int m = m0 + wm + i * 16 + lg * 4 + rr;
            const float bp = cvec[b * 256 + m];
            #pragma unroll
            for (int j = 0; j < 4; ++j) {
                const int n = n0 + wn + j * 16 + l15;
                ob[(size_t)m * HW + n] = acc[i][j][rr] + bp;
            }
        }
}

extern "C" void kernel_launch(void* const* d_in, const int* in_sizes, int n_in,
                              void* d_out, int out_size, void* d_ws, size_t ws_size,
                              hipStream_t stream) {
    const float* x     = (const float*)d_in[0];
    const float* Wqkv  = (const float*)d_in[1];
    const float* bqkv  = (const float*)d_in[2];
    const float* Wproj = (const float*)d_in[3];
    const float* bproj = (const float*)d_in[4];
    float* out = (float*)d_out;

    // ws layout (bytes):
    //   x_hi  :         0   67108864
    //   x_lo  :  67108864   67108864
    //   partG : 134217728   67108864   (8*32*256*256 f32)
    //   G     : 201326592    2097152
    //   attn  : 203423744     524288
    //   M     : 203948032    2097152
    //   P     : 206045184    1048576
    //   cvec  : 207093760       8192
    //   s     : 207101952       8192
    //   T     : 207110144    2097152   -> total ~199.5 MiB
    char* ws = (char*)d_ws;
    unsigned short* xh = (unsigned short*)(ws);
    unsigned short* xl = (unsigned short*)(ws + 67108864);
    float* partG = (float*)(ws + 134217728);
    float* G     = (float*)(ws + 201326592);
    float* attn  = (float*)(ws + 203423744);
    float* M     = (float*)(ws + 203948032);
    unsigned short* P = (unsigned short*)(ws + 206045184);
    float* cvec  = (float*)(ws + 207093760);
    float* s     = (float*)(ws + 207101952);
    float* T     = (float*)(ws + 207110144);

    cast_x   <<<2048,            256, 0, stream>>>(x, xh, xl, s);
    gram     <<<dim3(32, 8),     512, 0, stream>>>(xh, xl, partG);
    greduce  <<<2048,            256, 0, stream>>>(partG, G);
    tgemm    <<<dim3(4, 4, 8),   256, 0, stream>>>(G, Wqkv, T);
    logits_sm<<<32,              256, 0, stream>>>(T, Wqkv, bqkv, s, attn);
    build_M  <<<2048,            256, 0, stream>>>(attn, Wproj, M);
    build_P  <<<128,             256, 0, stream>>>(M, Wqkv, bqkv, bproj, P, cvec);
    out_gemm <<<dim3(128, 2, 8), 256, 0, stream>>>(P, xh, cvec, out);
}

// Round 5
// 229.862 us; speedup vs baseline: 1.6845x; 1.1426x over previous
//
#include <hip/hip_runtime.h>
#include <hip/hip_bf16.h>
#include <stdint.h>

// B=8, C=256, HW=16384, HEADS=4, HEAD_DIM=64, SCALE=1/8.
// G[b]=x x^T (split-bf16 MFMA from in-register hi/lo split of fp32 x);
// T[b] = Wq_all G[b]; logits = T_h Wk_h^T (+bias terms); attn = softmax;
// M = Wproj blockdiag(attn); P = M Wv; out = P x_hi + (M bv + bproj).

#define HW 16384
#define SCALE_F 0.125f
#define NF 16384.0f

typedef __attribute__((ext_vector_type(8))) short bf16x8;
typedef __attribute__((ext_vector_type(4))) float f32x4;

__device__ __forceinline__ unsigned short f2bf(float f) {
    union { float f; uint32_t u; } v; v.f = f;
    uint32_t u = v.u;
    return (unsigned short)((u + 0x7fffu + ((u >> 16) & 1u)) >> 16);  // RNE
}
__device__ __forceinline__ float bf2f(unsigned short s) {
    union { uint32_t u; float f; } v; v.u = ((uint32_t)s) << 16;
    return v.f;
}

// ---------------- K1: Gram, one 256x256 tile per (kc,b); fp32 x -> reg hi/lo -> swizzled LDS
__global__ __launch_bounds__(512) void gram(
        const float* __restrict__ x, float* __restrict__ partG,
        float* __restrict__ parts_s) {
    const int kc = blockIdx.x;    // 0..31, K-chunk of 512
    const int b  = blockIdx.y;
    __shared__ __align__(16) unsigned short Hs[2][256 * 32];
    __shared__ __align__(16) unsigned short Ls[2][256 * 32];
    const int tid = threadIdx.x, lane = tid & 63, w = tid >> 6;
    const int l15 = lane & 15, lg = lane >> 4;
    const int wr = w >> 1, wc = w & 1;          // 4x64-row x 2x128-col wave grid
    const int srow = tid >> 1, shalf = tid & 1; // staging: row, 16-col half
    const int m4 = (srow >> 1) & 3;             // swizzle key for this row
    const float* xb = x + (size_t)b * 256 * HW + (size_t)srow * HW + kc * 512 + shalf * 16;
    f32x4 acc[4][8] = {};
    float rs = 0.f;
    float4 ld[4];

#define LOADR(kstep)                                                            \
    {                                                                           \
        const float4* src = reinterpret_cast<const float4*>(xb + (kstep) * 32); \
        ld[0] = src[0]; ld[1] = src[1]; ld[2] = src[2]; ld[3] = src[3];         \
    }
#define STORE(sel)                                                              \
    {                                                                           \
        _Pragma("unroll")                                                       \
        for (int cq = 0; cq < 2; ++cq) {                                        \
            union { unsigned short u[8]; uint4 v; } Hu, Lu;                     \
            const float vv[8] = {ld[2*cq].x, ld[2*cq].y, ld[2*cq].z, ld[2*cq].w,\
                                 ld[2*cq+1].x, ld[2*cq+1].y, ld[2*cq+1].z, ld[2*cq+1].w}; \
            _Pragma("unroll")                                                   \
            for (int i = 0; i < 8; ++i) {                                       \
                Hu.u[i] = f2bf(vv[i]);                                          \
                Lu.u[i] = f2bf(vv[i] - bf2f(Hu.u[i]));                          \
                rs += vv[i];                                                    \
            }                                                                   \
            const int slot = ((shalf * 2 + cq) ^ m4) << 4;                      \
            *reinterpret_cast<uint4*>((char*)(&Hs[sel][0]) + srow * 64 + slot) = Hu.v; \
            *reinterpret_cast<uint4*>((char*)(&Ls[sel][0]) + srow * 64 + slot) = Lu.v; \
        }                                                                       \
    }
#define DO_MFMA(sel)                                                            \
    {                                                                           \
        bf16x8 fah[4], fal[4];                                                  \
        _Pragma("unroll")                                                       \
        for (int i = 0; i < 4; ++i) {                                           \
            const int row = wr * 64 + i * 16 + l15;                             \
            const int off = row * 64 + ((lg ^ ((row >> 1) & 3)) << 4);          \
            fah[i] = *reinterpret_cast<const bf16x8*>((const char*)&Hs[sel][0] + off); \
            fal[i] = *reinterpret_cast<const bf16x8*>((const char*)&Ls[sel][0] + off); \
        }                                                                       \
        _Pragma("unroll")                                                       \
        for (int j = 0; j < 8; ++j) {                                           \
            const int row = wc * 128 + j * 16 + l15;                            \
            const int off = row * 64 + ((lg ^ ((row >> 1) & 3)) << 4);          \
            const bf16x8 fbh = *reinterpret_cast<const bf16x8*>((const char*)&Hs[sel][0] + off); \
            const bf16x8 fbl = *reinterpret_cast<const bf16x8*>((const char*)&Ls[sel][0] + off); \
            _Pragma("unroll")                                                   \
            for (int i = 0; i < 4; ++i) {                                       \
                acc[i][j] = __builtin_amdgcn_mfma_f32_16x16x32_bf16(fah[i], fbh, acc[i][j], 0, 0, 0); \
                acc[i][j] = __builtin_amdgcn_mfma_f32_16x16x32_bf16(fah[i], fbl, acc[i][j], 0, 0, 0); \
                acc[i][j] = __builtin_amdgcn_mfma_f32_16x16x32_bf16(fal[i], fbh, acc[i][j], 0, 0, 0); \
            }                                                                   \
        }                                                                       \
    }

    LOADR(0);
    STORE(0);
    __syncthreads();
    for (int t = 0; t < 16; ++t) {
        if (t < 15) LOADR(t + 1);
        DO_MFMA(t & 1);
        if (t < 15) STORE((t + 1) & 1);
        __syncthreads();
    }
#undef LOADR
#undef STORE
#undef DO_MFMA

    // row-sum partials: threads 2r,2r+1 share row r
    rs += __shfl_xor(rs, 1);
    if ((tid & 1) == 0) parts_s[(size_t)(b * 32 + kc) * 256 + srow] = rs;

    float* pw = partG + (size_t)(b * 32 + kc) * 65536;
    #pragma unroll
    for (int i = 0; i < 4; ++i)
        #pragma unroll
        for (int rr = 0; rr < 4; ++rr) {
            const int m = wr * 64 + i * 16 + lg * 4 + rr;
            #pragma unroll
            for (int j = 0; j < 8; ++j)
                pw[m * 256 + wc * 128 + j * 16 + l15] = acc[i][j][rr];
        }
}

// ---------------- K2: G = sum over 32 chunks of partG
__global__ __launch_bounds__(256) void greduce(
        const float* __restrict__ partG, float* __restrict__ G) {
    const size_t idx = (size_t)blockIdx.x * 256 + threadIdx.x;  // 524288
    const int b = (int)(idx >> 16);
    const int i = (int)(idx & 65535);
    float sacc = 0.f;
    #pragma unroll
    for (int kc = 0; kc < 32; ++kc)
        sacc += partG[(size_t)(b * 32 + kc) * 65536 + i];
    G[idx] = sacc;
}

// ---------------- K2b: s = sum over 32 chunks of parts_s
__global__ void sreduce(const float* __restrict__ parts_s, float* __restrict__ s) {
    const int b = blockIdx.x, c = threadIdx.x;
    float a = 0.f;
    #pragma unroll
    for (int kc = 0; kc < 32; ++kc)
        a += parts_s[(size_t)(b * 32 + kc) * 256 + c];
    s[b * 256 + c] = a;
}

// ---------------- K3: T[b] = Wq_all (256x256) @ G[b] (256x256), fp32 tiled GEMM
__global__ __launch_bounds__(256) void tgemm(
        const float* __restrict__ G, const float* __restrict__ Wqkv,
        float* __restrict__ T) {
    const int c0 = blockIdx.x * 64;   // c' tile
    const int d0 = blockIdx.y * 64;   // d tile
    const int b  = blockIdx.z;
    __shared__ float Ws[64][68];
    __shared__ float Gs[64][68];
    const int tid = threadIdx.x;
    const float* Gb = G + (size_t)b * 65536;
    const int ry = (tid >> 4) * 4, cx = (tid & 15) * 4;
    const int r = tid >> 2, q = (tid & 3) * 16;
    float acc[4][4] = {};

    for (int cb = 0; cb < 4; ++cb) {
        __syncthreads();
        #pragma unroll
        for (int j = 0; j < 16; j += 4) {
            *reinterpret_cast<float4*>(&Ws[r][q + j]) =
                *reinterpret_cast<const float4*>(Wqkv + (size_t)(d0 + r) * 256 + cb * 64 + q + j);
            *reinterpret_cast<float4*>(&Gs[r][q + j]) =
                *reinterpret_cast<const float4*>(Gb + (size_t)(cb * 64 + r) * 256 + c0 + q + j);
        }
        __syncthreads();
        #pragma unroll 8
        for (int k = 0; k < 64; ++k) {
            const float4 g4 = *reinterpret_cast<const float4*>(&Gs[k][cx]);
            #pragma unroll
            for (int i = 0; i < 4; ++i) {
                const float a = Ws[ry + i][k];
                acc[i][0] += a * g4.x;
                acc[i][1] += a * g4.y;
                acc[i][2] += a * g4.z;
                acc[i][3] += a * g4.w;
            }
        }
    }
    float* Tb = T + (size_t)b * 65536;
    #pragma unroll
    for (int i = 0; i < 4; ++i)
        #pragma unroll
        for (int j = 0; j < 4; ++j)
            Tb[(size_t)(d0 + ry + i) * 256 + c0 + cx + j] = acc[i][j];
}

// ---------------- K4: per (b,h): logits = T_h Wk_h^T + bias; softmax -> attn
__global__ __launch_bounds__(256) void logits_sm(
        const float* __restrict__ T, const float* __restrict__ Wqkv,
        const float* __restrict__ bqkv, const float* __restrict__ s,
        float* __restrict__ attn) {
    const int bh = blockIdx.x, b = bh >> 2, h = bh & 3;
    const int tid = threadIdx.x;
    __shared__ float Ts[64][257];
    __shared__ float Wks[64][257];
    __shared__ float lgs[64][65];
    __shared__ float qs[64], ks[64];
    const float* Tb = T + (size_t)b * 65536 + (size_t)(h * 64) * 256;
    const float* Wq = Wqkv + (size_t)(h * 64) * 256;
    const float* Wk = Wqkv + (size_t)(256 + h * 64) * 256;

    {   // stage Ts, Wks
        const int r = tid >> 2, q = (tid & 3) * 64;
        #pragma unroll
        for (int j = 0; j < 64; j += 4) {
            const float4 t4 = *reinterpret_cast<const float4*>(Tb + (size_t)r * 256 + q + j);
            Ts[r][q + j + 0] = t4.x; Ts[r][q + j + 1] = t4.y;
            Ts[r][q + j + 2] = t4.z; Ts[r][q + j + 3] = t4.w;
            const float4 w4 = *reinterpret_cast<const float4*>(Wk + (size_t)r * 256 + q + j);
            Wks[r][q + j + 0] = w4.x; Wks[r][q + j + 1] = w4.y;
            Wks[r][q + j + 2] = w4.z; Wks[r][q + j + 3] = w4.w;
        }
    }
    if (tid < 128) {   // qs = Wq s_b, ks = Wk s_b (bias path)
        const int d = tid & 63;
        const float* wr = (tid < 64) ? (Wq + (size_t)d * 256) : (Wk + (size_t)d * 256);
        const float* sb = s + b * 256;
        float a = 0.f;
        for (int c = 0; c < 256; ++c) a += wr[c] * sb[c];
        if (tid < 64) qs[d] = a; else ks[d] = a;
    }
    __syncthreads();

    const int d4 = (tid >> 4) * 4, e4 = (tid & 15) * 4;
    float acc[4][4] = {};
    #pragma unroll 4
    for (int c = 0; c < 256; ++c) {
        float tv[4], wv[4];
        #pragma unroll
        for (int i = 0; i < 4; ++i) tv[i] = Ts[d4 + i][c];
        #pragma unroll
        for (int j = 0; j < 4; ++j) wv[j] = Wks[e4 + j][c];
        #pragma unroll
        for (int i = 0; i < 4; ++i)
            #pragma unroll
            for (int j = 0; j < 4; ++j)
                acc[i][j] += tv[i] * wv[j];
    }
    const float* bq = bqkv + h * 64;
    const float* bk = bqkv + 256 + h * 64;
    #pragma unroll
    for (int i = 0; i < 4; ++i) {
        const float bqi = bq[d4 + i], qsi = qs[d4 + i];
        #pragma unroll
        for (int j = 0; j < 4; ++j) {
            const int e = e4 + j;
            lgs[d4 + i][e] = SCALE_F * (acc[i][j] + bqi * ks[e] + bk[e] * qsi + NF * bqi * bk[e]);
        }
    }
    __syncthreads();
    if (tid < 64) {
        float m = -1e30f;
        for (int e = 0; e < 64; ++e) m = fmaxf(m, lgs[tid][e]);
        float sum = 0.f;
        for (int e = 0; e < 64; ++e) {
            const float ex = __expf(lgs[tid][e] - m);
            sum += ex;
            lgs[tid][e] = ex;
        }
        const float inv = 1.f / sum;
        float* ar = attn + ((size_t)bh * 64 + tid) * 64;
        for (int e = 0; e < 64; ++e) ar[e] = lgs[tid][e] * inv;
    }
}

// ---------------- K5: M[b][o][h*64+e] = sum_d Wproj[o][h*64+d] attn[b,h,d,e] (fp32)
__global__ __launch_bounds__(256) void build_M(
        const float* __restrict__ attn, const float* __restrict__ Wproj,
        float* __restrict__ M) {
    const int g = blockIdx.x * 256 + threadIdx.x;
    const int b = g >> 16, o = (g >> 8) & 255, cpx = g & 255;
    const int h = cpx >> 6, e = cpx & 63;
    const float* wrow = Wproj + (size_t)o * 256 + h * 64;
    const float* acol = attn + ((size_t)(b * 4 + h) * 64) * 64 + e;
    float sacc = 0.f;
    #pragma unroll
    for (int d = 0; d < 64; ++d) sacc += wrow[d] * acol[d * 64];
    M[g] = sacc;
}

// ---------------- K6: P[b] = M[b] Wv (bf16); cvec[b] = M[b] bv + bproj
__global__ __launch_bounds__(256) void build_P(
        const float* __restrict__ M, const float* __restrict__ Wqkv,
        const float* __restrict__ bqkv, const float* __restrict__ bproj,
        unsigned short* __restrict__ P, float* __restrict__ cvec) {
    const int b = blockIdx.x >> 4, oc = blockIdx.x & 15;   // 16 o-rows per block
    const int tid = threadIdx.x, c = tid;
    __shared__ float Wvs[32 * 256];
    __shared__ float Ms[16 * 256];
    for (int j = tid; j < 16 * 256; j += 256)
        Ms[j] = M[(size_t)b * 65536 + oc * 16 * 256 + j];
    float acc[16];
    #pragma unroll
    for (int o = 0; o < 16; ++o) acc[o] = 0.f;
    for (int cb2 = 0; cb2 < 8; ++cb2) {
        __syncthreads();
        for (int j = tid; j < 32 * 256; j += 256)
            Wvs[j] = Wqkv[(size_t)(512 + cb2 * 32) * 256 + j];
        __syncthreads();
        for (int c2 = 0; c2 < 32; ++c2) {
            const float wv = Wvs[c2 * 256 + c];
            #pragma unroll
            for (int o = 0; o < 16; ++o)
                acc[o] += Ms[o * 256 + cb2 * 32 + c2] * wv;
        }
    }
    #pragma unroll
    for (int o = 0; o < 16; ++o)
        P[(size_t)b * 65536 + (size_t)(oc * 16 + o) * 256 + c] = f2bf(acc[o]);
    if (tid < 16) {
        const int o = oc * 16 + tid;
        float a = bproj[o];
        for (int c2 = 0; c2 < 256; ++c2)
            a += M[(size_t)b * 65536 + (size_t)o * 256 + c2] * bqkv[512 + c2];
        cvec[b * 256 + o] = a;
    }
}

// ---------------- K7: out[b][o][n] = sum_c P[b][o][c] bf16(x[b][c][n]) + cvec[b][o]
// M-tile = 256 (full), N-tile = 128; x read once, converted in-register.
__global__ __launch_bounds__(512) void out_gemm(
        const unsigned short* __restrict__ P, const float* __restrict__ x,
        const float* __restrict__ cvec, float* __restrict__ out) {
    const int n0 = blockIdx.x * 128;
    const int b  = blockIdx.y;
    __shared__ __align__(16) unsigned short Bs[2][128 * 40];
    const int tid = threadIdx.x, lane = tid & 63, w = tid >> 6;
    const int wr = w >> 1, wc = w & 1;          // 4x64-row x 2x64-col wave grid
    const int l15 = lane & 15, lg = lane >> 4;
    const unsigned short* Pb = P + (size_t)b * 65536;
    const float* xb = x + (size_t)b * 256 * HW + n0;
    const int sn = tid & 127, skq = (tid >> 7) * 8;   // staging: col n, 8-k group
    f32x4 acc[4][4] = {};
    float bv[8];

#define BLOAD(k0)                                                               \
    {                                                                           \
        _Pragma("unroll")                                                       \
        for (int i = 0; i < 8; ++i)                                             \
            bv[i] = xb[(size_t)((k0) + skq + i) * HW + sn];                     \
    }
#define BSTORE(sel)                                                             \
    {                                                                           \
        union { unsigned short u[8]; uint4 v; } Bu;                             \
        _Pragma("unroll")                                                       \
        for (int i = 0; i < 8; ++i) Bu.u[i] = f2bf(bv[i]);                      \
        *reinterpret_cast<uint4*>(&Bs[sel][sn * 40 + skq]) = Bu.v;              \
    }

    BLOAD(0);
    BSTORE(0);
    __syncthreads();
    for (int t = 0; t < 8; ++t) {
        const int k0 = t * 32;
        if (t < 7) BLOAD(k0 + 32);
        bf16x8 fa[4];
        #pragma unroll
        for (int i = 0; i < 4; ++i)
            fa[i] = *reinterpret_cast<const bf16x8*>(
                Pb + (size_t)(wr * 64 + i * 16 + l15) * 256 + k0 + lg * 8);
        #pragma unroll
        for (int j = 0; j < 4; ++j) {
            const bf16x8 fb = *reinterpret_cast<const bf16x8*>(
                &Bs[t & 1][(wc * 64 + j * 16 + l15) * 40 + lg * 8]);
            #pragma unroll
            for (int i = 0; i < 4; ++i)
                acc[i][j] = __builtin_amdgcn_mfma_f32_16x16x32_bf16(fa[i], fb, acc[i][j], 0, 0, 0);
        }
        if (t < 7) BSTORE((t + 1) & 1);
        __syncthreads();
    }
#undef BLOAD
#undef BSTORE

    float* ob = out + (size_t)b * 256 * HW;
    #pragma unroll
    for (int i = 0; i < 4; ++i)
        #pragma unroll
        for (int rr = 0; rr < 4; ++rr) {
            const int m = wr * 64 + i * 16 + lg * 4 + rr;
            const float bp = cvec[b * 256 + m];
            #pragma unroll
            for (int j = 0; j < 4; ++j) {
                const int n = n0 + wc * 64 + j * 16 + l15;
                ob[(size_t)m * HW + n] = acc[i][j][rr] + bp;
            }
        }
}

extern "C" void kernel_launch(void* const* d_in, const int* in_sizes, int n_in,
                              void* d_out, int out_size, void* d_ws, size_t ws_size,
                              hipStream_t stream) {
    const float* x     = (const float*)d_in[0];
    const float* Wqkv  = (const float*)d_in[1];
    const float* bqkv  = (const float*)d_in[2];
    const float* Wproj = (const float*)d_in[3];
    const float* bproj = (const float*)d_in[4];
    float* out = (float*)d_out;

    // ws layout (bytes):
    //   partG  :        0   67108864   (8*32*256*256 f32)
    //   G      : 67108864    2097152
    //   attn   : 69206016     524288
    //   M      : 69730304    2097152
    //   P      : 71827456    1048576
    //   cvec   : 72876032       8192
    //   s      : 72884224       8192
    //   partsS : 72892416     262144   (8*32*256 f32)
    //   T      : 73154560    2097152   -> total ~71.8 MiB
    char* ws = (char*)d_ws;
    float* partG   = (float*)(ws);
    float* G       = (float*)(ws + 67108864);
    float* attn    = (float*)(ws + 69206016);
    float* M       = (float*)(ws + 69730304);
    unsigned short* P = (unsigned short*)(ws + 71827456);
    float* cvec    = (float*)(ws + 72876032);
    float* s       = (float*)(ws + 72884224);
    float* parts_s = (float*)(ws + 72892416);
    float* T       = (float*)(ws + 73154560);

    gram     <<<dim3(32, 8),   512, 0, stream>>>(x, partG, parts_s);
    greduce  <<<2048,          256, 0, stream>>>(partG, G);
    sreduce  <<<8,             256, 0, stream>>>(parts_s, s);
    tgemm    <<<dim3(4, 4, 8), 256, 0, stream>>>(G, Wqkv, T);
    logits_sm<<<32,            256, 0, stream>>>(T, Wqkv, bqkv, s, attn);
    build_M  <<<2048,          256, 0, stream>>>(attn, Wproj, M);
    build_P  <<<128,           256, 0, stream>>>(M, Wqkv, bqkv, bproj, P, cvec);
    out_gemm <<<dim3(128, 8),  512, 0, stream>>>(P, x, cvec, out);
}